// Round 4
// baseline (110.330 us; speedup 1.0000x reference)
//
#include <hip/hip_runtime.h>

#define NQ 4
#define DEPTH 2
#define BLK 256
#define K 4

typedef _Float16 v2h __attribute__((ext_vector_type(2)));

// dot2: f32 += f16[0]*f16[0] + f16[1]*f16[1]  (full-rate DL instruction).
// src0 may be an SGPR (max-1-SGPR-per-VALU rule) -> U rows live in SGPRs.
__device__ __forceinline__ float fdot2u(unsigned u, unsigned p, float acc) {
#if __has_builtin(__builtin_amdgcn_fdot2)
    return __builtin_amdgcn_fdot2(__builtin_bit_cast(v2h, u),
                                  __builtin_bit_cast(v2h, p), acc, false);
#else
    float d;
    asm("v_dot2_f32_f16 %0, %1, %2, %3" : "=v"(d) : "v"(u), "v"(p), "v"(acc));
    return d;
#endif
}
__device__ __forceinline__ unsigned pack2h(float a, float b) {
    return __builtin_bit_cast(unsigned, __builtin_amdgcn_cvt_pkrtz(a, b));
}

__device__ __forceinline__ float2 cmul(float2 a, float2 b) {
    return make_float2(a.x * b.x - a.y * b.y, a.x * b.y + a.y * b.x);
}
__device__ __forceinline__ float2 cadd(float2 a, float2 b) {
    return make_float2(a.x + b.x, a.y + b.y);
}

// Simulate basis column `col` of the fixed post-encoding circuit unitary.
__device__ __forceinline__ void build_u_col(const float* __restrict__ qw, int col,
                                            float2 amp[16]) {
#pragma unroll
    for (int i = 0; i < 16; i++)
        amp[i] = make_float2((i == col) ? 1.f : 0.f, 0.f);

#pragma unroll
    for (int layer = 0; layer < DEPTH; layer++) {
#pragma unroll
        for (int w = 0; w < NQ; w++) {
            const float* g = qw + (layer * NQ + w) * 3;
            float phi = g[0], theta = g[1], omega = g[2];
            float ch, sh, sp, cp, sm, cm;
            __sincosf(0.5f * theta, &sh, &ch);
            __sincosf(-0.5f * (phi + omega), &sp, &cp);
            __sincosf(0.5f * (phi - omega), &sm, &cm);
            float2 U00 = make_float2(cp * ch, sp * ch);
            float2 U01 = make_float2(-cm * sh, -sm * sh);
            float2 U10 = make_float2(cm * sh, -sm * sh);
            float2 U11 = make_float2(cp * ch, -sp * ch);
            const int mask = 8 >> w;                      // wire w = bit (3-w)
#pragma unroll
            for (int i0 = 0; i0 < 16; i0++) {
                if (i0 & mask) continue;
                const int i1 = i0 | mask;
                float2 a0 = amp[i0], a1 = amp[i1];
                amp[i0] = cadd(cmul(U00, a0), cmul(U01, a1));
                amp[i1] = cadd(cmul(U10, a0), cmul(U11, a1));
            }
        }
        // CNOT ring: (0,1),(1,2),(2,3),(3,0)
#pragma unroll
        for (int c = 0; c < NQ; c++) {
            const int t = (c + 1) & 3;
            const int cmsk = 8 >> c, tmsk = 8 >> t;
#pragma unroll
            for (int i = 0; i < 16; i++) {
                if ((i & cmsk) && !(i & tmsk)) {
                    float2 tmp = amp[i];
                    amp[i] = amp[i | tmsk];
                    amp[i | tmsk] = tmp;
                }
            }
        }
    }
}

// Single fused kernel, deliberately NOT using d_ws: the harness re-poisons the
// 256 MiB ws arena every iteration; a kernel that reads ws has a WAR hazard
// against the next poison-fill, which serializes the whole graph (rounds 0/3:
// fill_ws -> build -> main -> fill_ws' ...). A ws-free kernel lets the ws fill
// run concurrently with compute (round 2 showed ~22 us of such overlap).
// U is built block-locally (16 lanes of wave 0), staged through 1 KB LDS, and
// pinned into SGPRs via readfirstlane so the dot2 loop has zero vector loads.
__global__ __launch_bounds__(BLK) void vqc_fused(const float* __restrict__ x,
                                                 const float* __restrict__ qw,
                                                 float* __restrict__ out, int B) {
    // LDS: 256 dwords: [0..127] re plane (row r = dwords 8r..8r+7, dword q =
    // f16 pair (j=2q,2q+1)), [128..255] im plane.
    __shared__ __align__(16) unsigned Upl[256];

    const int tid = threadIdx.x;
    const int base = blockIdx.x * (BLK * K) + tid;

    // ---- issue global x loads first: HBM latency hides under the U build ----
    bool val[K];
    float4 v[K];
#pragma unroll
    for (int k = 0; k < K; k++) {
        const int b = base + k * BLK;
        val[k] = (b < B);
        v[k] = val[k] ? ((const float4*)x)[b] : make_float4(0.f, 0.f, 0.f, 0.f);
    }

    if (tid < 16) {
        float2 amp[16];
        build_u_col(qw, tid, amp);
        _Float16* wre = (_Float16*)Upl;
        _Float16* wim = wre + 256;
#pragma unroll
        for (int i = 0; i < 16; i++) {
            wre[i * 16 + tid] = (_Float16)amp[i].x;
            wim[i * 16 + tid] = (_Float16)amp[i].y;
        }
    }
    __syncthreads();

    // ---- RY encoding -> psi in f16 pairs over j ----
    unsigned psh[K][8];     // psh[el][q] = {psi[2q], psi[2q+1]} as 2xf16
#pragma unroll
    for (int k = 0; k < K; k++) {
        const float R = 0.07957747154594767f;   // 1/(4*pi): sin(x/2)=v_sin(x*R)
        float s0 = __builtin_amdgcn_sinf(v[k].x * R), c0 = __builtin_amdgcn_cosf(v[k].x * R);
        float s1 = __builtin_amdgcn_sinf(v[k].y * R), c1 = __builtin_amdgcn_cosf(v[k].y * R);
        float s2 = __builtin_amdgcn_sinf(v[k].z * R), c2 = __builtin_amdgcn_cosf(v[k].z * R);
        float s3 = __builtin_amdgcn_sinf(v[k].w * R), c3 = __builtin_amdgcn_cosf(v[k].w * R);
        const float a01[4] = {c0 * c1, c0 * s1, s0 * c1, s0 * s1};
        const float a23[4] = {c2 * c3, c2 * s3, s2 * c3, s2 * s3};
#pragma unroll
        for (int q = 0; q < 8; q++) {
            const int j0 = 2 * q, j1 = 2 * q + 1;
            psh[k][q] = pack2h(a01[j0 >> 2] * a23[j0 & 3], a01[j1 >> 2] * a23[j1 & 3]);
        }
    }

    float ow0[K], ow1[K], ow2[K], ow3[K];
#pragma unroll
    for (int k = 0; k < K; k++) { ow0[k] = 0.f; ow1[k] = 0.f; ow2[k] = 0.f; ow3[k] = 0.f; }

    // ---- matvec: row-pair loop; U pinned to SGPRs via broadcast LDS read +
    // readfirstlane (32 VOP1/rp) so the inner dot2 loop has zero vector loads.
#pragma unroll 1
    for (int rp = 0; rp < 8; rp++) {
        unsigned ur[16], ui[16];   // [0..7]=row 2rp, [8..15]=row 2rp+1
#pragma unroll
        for (int j = 0; j < 16; j++) {
            ur[j] = __builtin_amdgcn_readfirstlane(Upl[rp * 16 + j]);
            ui[j] = __builtin_amdgcn_readfirstlane(Upl[128 + rp * 16 + j]);
        }

        const float f3 = (rp & 4) ? -1.f : 1.f;   // bit3 of row -> wire0
        const float f2 = (rp & 2) ? -1.f : 1.f;   // bit2 -> wire1
        const float f1 = (rp & 1) ? -1.f : 1.f;   // bit1 -> wire2

#pragma unroll
        for (int k = 0; k < K; k++) {
            float fre0 = 0.f, fim0 = 0.f, fre1 = 0.f, fim1 = 0.f;
#pragma unroll
            for (int q = 0; q < 8; q++) {
                const unsigned p = psh[k][q];
                fre0 = fdot2u(ur[q], p, fre0);
                fim0 = fdot2u(ui[q], p, fim0);
                fre1 = fdot2u(ur[8 + q], p, fre1);
                fim1 = fdot2u(ui[8 + q], p, fim1);
            }
            const float p0 = fmaf(fim0, fim0, fre0 * fre0);
            const float p1 = fmaf(fim1, fim1, fre1 * fre1);
            const float s = p0 + p1, d = p0 - p1;
            ow0[k] = fmaf(f3, s, ow0[k]);
            ow1[k] = fmaf(f2, s, ow1[k]);
            ow2[k] = fmaf(f1, s, ow2[k]);
            ow3[k] += d;                          // bit0 -> wire3
        }
    }

#pragma unroll
    for (int k = 0; k < K; k++) {
        const int b = base + k * BLK;
        if (val[k])
            ((float4*)out)[b] = make_float4(ow0[k], ow1[k], ow2[k], ow3[k]);
    }
}

extern "C" void kernel_launch(void* const* d_in, const int* in_sizes, int n_in,
                              void* d_out, int out_size, void* d_ws, size_t ws_size,
                              hipStream_t stream) {
    const float* x  = (const float*)d_in[0];
    const float* qw = (const float*)d_in[1];
    float* out = (float*)d_out;
    const int B = in_sizes[0] / NQ;
    const int blocks = (B + BLK * K - 1) / (BLK * K);

    (void)d_ws; (void)ws_size;   // intentionally unused: keeps ws poison-fill off
                                 // the critical path (no WAR hazard with it)
    vqc_fused<<<blocks, BLK, 0, stream>>>(x, qw, out, B);
}

// Round 5
// 108.071 us; speedup vs baseline: 1.0209x; 1.0209x over previous
//
#include <hip/hip_runtime.h>

#define NQ 4
#define DEPTH 2
#define BLK 256
#define K 4

typedef _Float16 v2h __attribute__((ext_vector_type(2)));

// dot2: f32 += f16[0]*f16[0] + f16[1]*f16[1]  (full-rate DL instruction)
__device__ __forceinline__ float fdot2u(unsigned u, unsigned p, float acc) {
#if __has_builtin(__builtin_amdgcn_fdot2)
    return __builtin_amdgcn_fdot2(__builtin_bit_cast(v2h, u),
                                  __builtin_bit_cast(v2h, p), acc, false);
#else
    float d;
    asm("v_dot2_f32_f16 %0, %1, %2, %3" : "=v"(d) : "v"(u), "v"(p), "v"(acc));
    return d;
#endif
}
__device__ __forceinline__ unsigned pack2h(float a, float b) {
    return __builtin_bit_cast(unsigned, __builtin_amdgcn_cvt_pkrtz(a, b));
}

__device__ __forceinline__ float2 cmul(float2 a, float2 b) {
    return make_float2(a.x * b.x - a.y * b.y, a.x * b.y + a.y * b.x);
}
__device__ __forceinline__ float2 cadd(float2 a, float2 b) {
    return make_float2(a.x + b.x, a.y + b.y);
}

// Simulate basis column `col` of the fixed post-encoding circuit unitary.
__device__ __forceinline__ void build_u_col(const float* __restrict__ qw, int col,
                                            float2 amp[16]) {
#pragma unroll
    for (int i = 0; i < 16; i++)
        amp[i] = make_float2((i == col) ? 1.f : 0.f, 0.f);

#pragma unroll
    for (int layer = 0; layer < DEPTH; layer++) {
#pragma unroll
        for (int w = 0; w < NQ; w++) {
            const float* g = qw + (layer * NQ + w) * 3;
            float phi = g[0], theta = g[1], omega = g[2];
            float ch, sh, sp, cp, sm, cm;
            __sincosf(0.5f * theta, &sh, &ch);
            __sincosf(-0.5f * (phi + omega), &sp, &cp);
            __sincosf(0.5f * (phi - omega), &sm, &cm);
            float2 U00 = make_float2(cp * ch, sp * ch);
            float2 U01 = make_float2(-cm * sh, -sm * sh);
            float2 U10 = make_float2(cm * sh, -sm * sh);
            float2 U11 = make_float2(cp * ch, -sp * ch);
            const int mask = 8 >> w;                      // wire w = bit (3-w)
#pragma unroll
            for (int i0 = 0; i0 < 16; i0++) {
                if (i0 & mask) continue;
                const int i1 = i0 | mask;
                float2 a0 = amp[i0], a1 = amp[i1];
                amp[i0] = cadd(cmul(U00, a0), cmul(U01, a1));
                amp[i1] = cadd(cmul(U10, a0), cmul(U11, a1));
            }
        }
        // CNOT ring: (0,1),(1,2),(2,3),(3,0)
#pragma unroll
        for (int c = 0; c < NQ; c++) {
            const int t = (c + 1) & 3;
            const int cmsk = 8 >> c, tmsk = 8 >> t;
#pragma unroll
            for (int i = 0; i < 16; i++) {
                if ((i & cmsk) && !(i & tmsk)) {
                    float2 tmp = amp[i];
                    amp[i] = amp[i | tmsk];
                    amp[i | tmsk] = tmp;
                }
            }
        }
    }
}

// Fused, ws-free kernel (ws-free => the 256 MiB ws poison-fill has no hazard
// with us and overlaps compute; rounds 2/4 measured ~22 us of such overlap).
// The matvec body is the round-0 proven-fast version (LDS -> uint4 -> dot2,
// ~13-16 us standalone). Fusing the build previously collapsed VGPRs to 36-40
// and tripled the loop cost (compiler rematerialized the psh encode inside the
// rp loop). Countermeasures: asm-pin each psh value as an opaque VGPR (no
// remat, no sinking) and __launch_bounds__(256,2) (VGPR cap 128 > ~80 live).
__global__ __launch_bounds__(BLK, 2) void vqc_fused(const float* __restrict__ x,
                                                    const float* __restrict__ qw,
                                                    float* __restrict__ out, int B) {
    // LDS: 256 dwords: [0..127] re plane (row r = dwords 8r..8r+7, dword q =
    // f16 pair (j=2q,2q+1)), [128..255] im plane.
    __shared__ __align__(16) unsigned Upl[256];

    const int tid = threadIdx.x;
    const int base = blockIdx.x * (BLK * K) + tid;

    // ---- issue global x loads first: HBM latency hides under the U build ----
    bool val[K];
    float4 v[K];
#pragma unroll
    for (int k = 0; k < K; k++) {
        const int b = base + k * BLK;
        val[k] = (b < B);
        v[k] = val[k] ? ((const float4*)x)[b] : make_float4(0.f, 0.f, 0.f, 0.f);
    }

    // Build in lanes 0..15 of wave 0 only; waves 1-3 fall through to their
    // psh encode and then the barrier (they don't burn issue slots on build).
    if (tid < 16) {
        float2 amp[16];
        build_u_col(qw, tid, amp);
        _Float16* wre = (_Float16*)Upl;
        _Float16* wim = wre + 256;
#pragma unroll
        for (int i = 0; i < 16; i++) {
            wre[i * 16 + tid] = (_Float16)amp[i].x;
            wim[i * 16 + tid] = (_Float16)amp[i].y;
        }
    }

    // ---- RY encoding -> psi in f16 pairs over j (independent of LDS; waves
    // 1-3 do this while wave 0 is still building) ----
    unsigned psh[K][8];     // psh[el][q] = {psi[2q], psi[2q+1]} as 2xf16
#pragma unroll
    for (int k = 0; k < K; k++) {
        const float R = 0.07957747154594767f;   // 1/(4*pi): sin(x/2)=v_sin(x*R)
        float s0 = __builtin_amdgcn_sinf(v[k].x * R), c0 = __builtin_amdgcn_cosf(v[k].x * R);
        float s1 = __builtin_amdgcn_sinf(v[k].y * R), c1 = __builtin_amdgcn_cosf(v[k].y * R);
        float s2 = __builtin_amdgcn_sinf(v[k].z * R), c2 = __builtin_amdgcn_cosf(v[k].z * R);
        float s3 = __builtin_amdgcn_sinf(v[k].w * R), c3 = __builtin_amdgcn_cosf(v[k].w * R);
        const float a01[4] = {c0 * c1, c0 * s1, s0 * c1, s0 * s1};
        const float a23[4] = {c2 * c3, c2 * s3, s2 * c3, s2 * s3};
#pragma unroll
        for (int q = 0; q < 8; q++) {
            const int j0 = 2 * q, j1 = 2 * q + 1;
            psh[k][q] = pack2h(a01[j0 >> 2] * a23[j0 & 3], a01[j1 >> 2] * a23[j1 & 3]);
        }
    }
    // Pin psh into VGPRs as opaque values: forbids rematerialization of the
    // sincos/pack chain inside the rp loop and spill-to-scratch of the array.
#pragma unroll
    for (int k = 0; k < K; k++)
#pragma unroll
        for (int q = 0; q < 8; q++)
            asm volatile("" : "+v"(psh[k][q]));

    __syncthreads();

    float ow0[K], ow1[K], ow2[K], ow3[K];
#pragma unroll
    for (int k = 0; k < K; k++) { ow0[k] = 0.f; ow1[k] = 0.f; ow2[k] = 0.f; ow3[k] = 0.f; }

    // ---- matvec: row-pair loop (round-0 proven-fast body, verbatim) ----
#pragma unroll 1
    for (int rp = 0; rp < 8; rp++) {
        const int r0 = 2 * rp;
        const uint4 re0a = *(const uint4*)&Upl[r0 * 8];
        const uint4 re0b = *(const uint4*)&Upl[r0 * 8 + 4];
        const uint4 re1a = *(const uint4*)&Upl[(r0 + 1) * 8];
        const uint4 re1b = *(const uint4*)&Upl[(r0 + 1) * 8 + 4];
        const uint4 im0a = *(const uint4*)&Upl[128 + r0 * 8];
        const uint4 im0b = *(const uint4*)&Upl[128 + r0 * 8 + 4];
        const uint4 im1a = *(const uint4*)&Upl[128 + (r0 + 1) * 8];
        const uint4 im1b = *(const uint4*)&Upl[128 + (r0 + 1) * 8 + 4];
        const unsigned ur0[8] = {re0a.x, re0a.y, re0a.z, re0a.w, re0b.x, re0b.y, re0b.z, re0b.w};
        const unsigned ur1[8] = {re1a.x, re1a.y, re1a.z, re1a.w, re1b.x, re1b.y, re1b.z, re1b.w};
        const unsigned ui0[8] = {im0a.x, im0a.y, im0a.z, im0a.w, im0b.x, im0b.y, im0b.z, im0b.w};
        const unsigned ui1[8] = {im1a.x, im1a.y, im1a.z, im1a.w, im1b.x, im1b.y, im1b.z, im1b.w};

        const float f3 = (rp & 4) ? -1.f : 1.f;   // bit3 of row -> wire0
        const float f2 = (rp & 2) ? -1.f : 1.f;   // bit2 -> wire1
        const float f1 = (rp & 1) ? -1.f : 1.f;   // bit1 -> wire2

#pragma unroll
        for (int k = 0; k < K; k++) {
            float fre0 = 0.f, fim0 = 0.f, fre1 = 0.f, fim1 = 0.f;
#pragma unroll
            for (int q = 0; q < 8; q++) {
                const unsigned p = psh[k][q];
                fre0 = fdot2u(ur0[q], p, fre0);
                fim0 = fdot2u(ui0[q], p, fim0);
                fre1 = fdot2u(ur1[q], p, fre1);
                fim1 = fdot2u(ui1[q], p, fim1);
            }
            const float p0 = fmaf(fim0, fim0, fre0 * fre0);
            const float p1 = fmaf(fim1, fim1, fre1 * fre1);
            const float s = p0 + p1, d = p0 - p1;
            ow0[k] = fmaf(f3, s, ow0[k]);
            ow1[k] = fmaf(f2, s, ow1[k]);
            ow2[k] = fmaf(f1, s, ow2[k]);
            ow3[k] += d;                          // bit0 -> wire3
        }
    }

#pragma unroll
    for (int k = 0; k < K; k++) {
        const int b = base + k * BLK;
        if (val[k])
            ((float4*)out)[b] = make_float4(ow0[k], ow1[k], ow2[k], ow3[k]);
    }
}

extern "C" void kernel_launch(void* const* d_in, const int* in_sizes, int n_in,
                              void* d_out, int out_size, void* d_ws, size_t ws_size,
                              hipStream_t stream) {
    const float* x  = (const float*)d_in[0];
    const float* qw = (const float*)d_in[1];
    float* out = (float*)d_out;
    const int B = in_sizes[0] / NQ;
    const int blocks = (B + BLK * K - 1) / (BLK * K);

    (void)d_ws; (void)ws_size;   // intentionally unused: keeps the ws poison-fill
                                 // off our critical path (no WAR hazard)
    vqc_fused<<<blocks, BLK, 0, stream>>>(x, qw, out, B);
}

// Round 6
// 107.275 us; speedup vs baseline: 1.0285x; 1.0074x over previous
//
#include <hip/hip_runtime.h>

#define NQ 4
#define DEPTH 2
#define BLK 256
#define K 4

typedef _Float16 v2h __attribute__((ext_vector_type(2)));

// dot2: f32 += f16[0]*f16[0] + f16[1]*f16[1]  (full-rate DL instruction)
__device__ __forceinline__ float fdot2u(unsigned u, unsigned p, float acc) {
#if __has_builtin(__builtin_amdgcn_fdot2)
    return __builtin_amdgcn_fdot2(__builtin_bit_cast(v2h, u),
                                  __builtin_bit_cast(v2h, p), acc, false);
#else
    float d;
    asm("v_dot2_f32_f16 %0, %1, %2, %3" : "=v"(d) : "v"(u), "v"(p), "v"(acc));
    return d;
#endif
}
__device__ __forceinline__ unsigned pack2h(float a, float b) {
    return __builtin_bit_cast(unsigned, __builtin_amdgcn_cvt_pkrtz(a, b));
}

__device__ __forceinline__ float2 cmul(float2 a, float2 b) {
    return make_float2(a.x * b.x - a.y * b.y, a.x * b.y + a.y * b.x);
}
__device__ __forceinline__ float2 cadd(float2 a, float2 b) {
    return make_float2(a.x + b.x, a.y + b.y);
}

// Simulate basis column `col` of the fixed post-encoding circuit unitary.
__device__ void build_u_col(const float* __restrict__ qw, int col, float2 amp[16]) {
#pragma unroll
    for (int i = 0; i < 16; i++)
        amp[i] = make_float2((i == col) ? 1.f : 0.f, 0.f);

#pragma unroll
    for (int layer = 0; layer < DEPTH; layer++) {
#pragma unroll
        for (int w = 0; w < NQ; w++) {
            const float* g = qw + (layer * NQ + w) * 3;
            float phi = g[0], theta = g[1], omega = g[2];
            float ch, sh, sp, cp, sm, cm;
            __sincosf(0.5f * theta, &sh, &ch);
            __sincosf(-0.5f * (phi + omega), &sp, &cp);
            __sincosf(0.5f * (phi - omega), &sm, &cm);
            float2 U00 = make_float2(cp * ch, sp * ch);
            float2 U01 = make_float2(-cm * sh, -sm * sh);
            float2 U10 = make_float2(cm * sh, -sm * sh);
            float2 U11 = make_float2(cp * ch, -sp * ch);
            const int mask = 8 >> w;                      // wire w = bit (3-w)
#pragma unroll
            for (int i0 = 0; i0 < 16; i0++) {
                if (i0 & mask) continue;
                const int i1 = i0 | mask;
                float2 a0 = amp[i0], a1 = amp[i1];
                amp[i0] = cadd(cmul(U00, a0), cmul(U01, a1));
                amp[i1] = cadd(cmul(U10, a0), cmul(U11, a1));
            }
        }
        // CNOT ring: (0,1),(1,2),(2,3),(3,0)
#pragma unroll
        for (int c = 0; c < NQ; c++) {
            const int t = (c + 1) & 3;
            const int cmsk = 8 >> c, tmsk = 8 >> t;
#pragma unroll
            for (int i = 0; i < 16; i++) {
                if ((i & cmsk) && !(i & tmsk)) {
                    float2 tmp = amp[i];
                    amp[i] = amp[i | tmsk];
                    amp[i | tmsk] = tmp;
                }
            }
        }
    }
}

// NOINLINE: this is the whole point. Rounds 2/4/5 showed that when the ~1300-
// instruction build body is inlined, the register allocator sizes the ENTIRE
// kernel at 36-40 VGPRs, which cannot hold the matvec's ~80-reg live set ->
// hidden spill/reload in the hot loop, 43 us vs ~14 us for the identical body
// in a build-free kernel (rounds 0/3). noinline gives the build its own
// allocation region; the matvec allocates as if the build didn't exist.
__device__ __noinline__ void build_u_into_lds(const float* __restrict__ qw,
                                              unsigned* Upl, int tid) {
    if (tid < 16) {
        float2 amp[16];
        build_u_col(qw, tid, amp);
        _Float16* wre = (_Float16*)Upl;
        _Float16* wim = wre + 256;
#pragma unroll
        for (int i = 0; i < 16; i++) {
            wre[i * 16 + tid] = (_Float16)amp[i].x;
            wim[i * 16 + tid] = (_Float16)amp[i].y;
        }
    }
}

// Fused, ws-free kernel. ws-free => the 256 MiB ws poison-fill has no hazard
// against us and overlaps compute (~22-24 us measured, rounds 2/4/5).
// Matvec body = round-0 proven-fast version (LDS -> uint4 -> dot2).
__global__ __launch_bounds__(BLK) void vqc_fused(const float* __restrict__ x,
                                                 const float* __restrict__ qw,
                                                 float* __restrict__ out, int B) {
    // LDS: 256 dwords: [0..127] re plane (row r = dwords 8r..8r+7, dword q =
    // f16 pair (j=2q,2q+1)), [128..255] im plane.
    __shared__ __align__(16) unsigned Upl[256];

    const int tid = threadIdx.x;
    const int base = blockIdx.x * (BLK * K) + tid;

    // ---- issue global x loads first: HBM latency hides under the U build ----
    bool val[K];
    float4 v[K];
#pragma unroll
    for (int k = 0; k < K; k++) {
        const int b = base + k * BLK;
        val[k] = (b < B);
        v[k] = val[k] ? ((const float4*)x)[b] : make_float4(0.f, 0.f, 0.f, 0.f);
    }

    // Build in lanes 0..15 of wave 0 (opaque call; waves 1-3 fall through).
    build_u_into_lds(qw, Upl, tid);

    // ---- RY encoding -> psi in f16 pairs over j ----
    unsigned psh[K][8];     // psh[el][q] = {psi[2q], psi[2q+1]} as 2xf16
#pragma unroll
    for (int k = 0; k < K; k++) {
        const float R = 0.07957747154594767f;   // 1/(4*pi): sin(x/2)=v_sin(x*R)
        float s0 = __builtin_amdgcn_sinf(v[k].x * R), c0 = __builtin_amdgcn_cosf(v[k].x * R);
        float s1 = __builtin_amdgcn_sinf(v[k].y * R), c1 = __builtin_amdgcn_cosf(v[k].y * R);
        float s2 = __builtin_amdgcn_sinf(v[k].z * R), c2 = __builtin_amdgcn_cosf(v[k].z * R);
        float s3 = __builtin_amdgcn_sinf(v[k].w * R), c3 = __builtin_amdgcn_cosf(v[k].w * R);
        const float a01[4] = {c0 * c1, c0 * s1, s0 * c1, s0 * s1};
        const float a23[4] = {c2 * c3, c2 * s3, s2 * c3, s2 * s3};
#pragma unroll
        for (int q = 0; q < 8; q++) {
            const int j0 = 2 * q, j1 = 2 * q + 1;
            psh[k][q] = pack2h(a01[j0 >> 2] * a23[j0 & 3], a01[j1 >> 2] * a23[j1 & 3]);
        }
    }

    __syncthreads();

    float ow0[K], ow1[K], ow2[K], ow3[K];
#pragma unroll
    for (int k = 0; k < K; k++) { ow0[k] = 0.f; ow1[k] = 0.f; ow2[k] = 0.f; ow3[k] = 0.f; }

    // ---- matvec: row-pair loop (round-0 proven-fast body, verbatim) ----
#pragma unroll 1
    for (int rp = 0; rp < 8; rp++) {
        const int r0 = 2 * rp;
        const uint4 re0a = *(const uint4*)&Upl[r0 * 8];
        const uint4 re0b = *(const uint4*)&Upl[r0 * 8 + 4];
        const uint4 re1a = *(const uint4*)&Upl[(r0 + 1) * 8];
        const uint4 re1b = *(const uint4*)&Upl[(r0 + 1) * 8 + 4];
        const uint4 im0a = *(const uint4*)&Upl[128 + r0 * 8];
        const uint4 im0b = *(const uint4*)&Upl[128 + r0 * 8 + 4];
        const uint4 im1a = *(const uint4*)&Upl[128 + (r0 + 1) * 8];
        const uint4 im1b = *(const uint4*)&Upl[128 + (r0 + 1) * 8 + 4];
        const unsigned ur0[8] = {re0a.x, re0a.y, re0a.z, re0a.w, re0b.x, re0b.y, re0b.z, re0b.w};
        const unsigned ur1[8] = {re1a.x, re1a.y, re1a.z, re1a.w, re1b.x, re1b.y, re1b.z, re1b.w};
        const unsigned ui0[8] = {im0a.x, im0a.y, im0a.z, im0a.w, im0b.x, im0b.y, im0b.z, im0b.w};
        const unsigned ui1[8] = {im1a.x, im1a.y, im1a.z, im1a.w, im1b.x, im1b.y, im1b.z, im1b.w};

        const float f3 = (rp & 4) ? -1.f : 1.f;   // bit3 of row -> wire0
        const float f2 = (rp & 2) ? -1.f : 1.f;   // bit2 -> wire1
        const float f1 = (rp & 1) ? -1.f : 1.f;   // bit1 -> wire2

#pragma unroll
        for (int k = 0; k < K; k++) {
            float fre0 = 0.f, fim0 = 0.f, fre1 = 0.f, fim1 = 0.f;
#pragma unroll
            for (int q = 0; q < 8; q++) {
                const unsigned p = psh[k][q];
                fre0 = fdot2u(ur0[q], p, fre0);
                fim0 = fdot2u(ui0[q], p, fim0);
                fre1 = fdot2u(ur1[q], p, fre1);
                fim1 = fdot2u(ui1[q], p, fim1);
            }
            const float p0 = fmaf(fim0, fim0, fre0 * fre0);
            const float p1 = fmaf(fim1, fim1, fre1 * fre1);
            const float s = p0 + p1, d = p0 - p1;
            ow0[k] = fmaf(f3, s, ow0[k]);
            ow1[k] = fmaf(f2, s, ow1[k]);
            ow2[k] = fmaf(f1, s, ow2[k]);
            ow3[k] += d;                          // bit0 -> wire3
        }
    }

#pragma unroll
    for (int k = 0; k < K; k++) {
        const int b = base + k * BLK;
        if (val[k])
            ((float4*)out)[b] = make_float4(ow0[k], ow1[k], ow2[k], ow3[k]);
    }
}

extern "C" void kernel_launch(void* const* d_in, const int* in_sizes, int n_in,
                              void* d_out, int out_size, void* d_ws, size_t ws_size,
                              hipStream_t stream) {
    const float* x  = (const float*)d_in[0];
    const float* qw = (const float*)d_in[1];
    float* out = (float*)d_out;
    const int B = in_sizes[0] / NQ;
    const int blocks = (B + BLK * K - 1) / (BLK * K);

    (void)d_ws; (void)ws_size;   // intentionally unused: keeps the ws poison-fill
                                 // off our critical path (no WAR hazard)
    vqc_fused<<<blocks, BLK, 0, stream>>>(x, qw, out, B);
}

// Round 7
// 104.150 us; speedup vs baseline: 1.0593x; 1.0300x over previous
//
#include <hip/hip_runtime.h>

// FINAL (session best, reproduces 105.5-105.8 us):
// Split config: 1-block build kernel writes the 16x16 f16 unitary planes into
// ws; the main kernel pins U rows into SGPRs (uniform loads + readfirstlane)
// so the 256-dot2/element hot loop has zero vector loads.
// Budget: 2x 268MB harness poison-fills @ 6.2 TB/s = 86.6 us (immovable, at
// the memset BW ceiling) + build dispatch ~4 us + main ~14 us (floor ~10-13:
// 64 MB traffic @ 6.3 TB/s, 8M wave-dot2s VALU). Fused/ws-free/overlap
// variants all measured 107-110 total (rounds 1/2/4/5/6) -> serial split wins.

#define NQ 4
#define DEPTH 2
#define BLK 256
#define K 4

typedef _Float16 v2h __attribute__((ext_vector_type(2)));

// dot2: f32 += f16[0]*f16[0] + f16[1]*f16[1]  (full-rate DL instruction).
// src0 may be an SGPR (max-1-SGPR-per-VALU rule) -> U rows live in SGPRs.
__device__ __forceinline__ float fdot2u(unsigned u, unsigned p, float acc) {
#if __has_builtin(__builtin_amdgcn_fdot2)
    return __builtin_amdgcn_fdot2(__builtin_bit_cast(v2h, u),
                                  __builtin_bit_cast(v2h, p), acc, false);
#else
    float d;
    asm("v_dot2_f32_f16 %0, %1, %2, %3" : "=v"(d) : "v"(u), "v"(p), "v"(acc));
    return d;
#endif
}
__device__ __forceinline__ unsigned pack2h(float a, float b) {
    return __builtin_bit_cast(unsigned, __builtin_amdgcn_cvt_pkrtz(a, b));
}

__device__ __forceinline__ float2 cmul(float2 a, float2 b) {
    return make_float2(a.x * b.x - a.y * b.y, a.x * b.y + a.y * b.x);
}
__device__ __forceinline__ float2 cadd(float2 a, float2 b) {
    return make_float2(a.x + b.x, a.y + b.y);
}

// Simulate basis column `col` of the fixed post-encoding circuit unitary.
__device__ __forceinline__ void build_u_col(const float* __restrict__ qw, int col,
                                            float2 amp[16]) {
#pragma unroll
    for (int i = 0; i < 16; i++)
        amp[i] = make_float2((i == col) ? 1.f : 0.f, 0.f);

#pragma unroll
    for (int layer = 0; layer < DEPTH; layer++) {
#pragma unroll
        for (int w = 0; w < NQ; w++) {
            const float* g = qw + (layer * NQ + w) * 3;
            float phi = g[0], theta = g[1], omega = g[2];
            float ch, sh, sp, cp, sm, cm;
            __sincosf(0.5f * theta, &sh, &ch);
            __sincosf(-0.5f * (phi + omega), &sp, &cp);
            __sincosf(0.5f * (phi - omega), &sm, &cm);
            float2 U00 = make_float2(cp * ch, sp * ch);
            float2 U01 = make_float2(-cm * sh, -sm * sh);
            float2 U10 = make_float2(cm * sh, -sm * sh);
            float2 U11 = make_float2(cp * ch, -sp * ch);
            const int mask = 8 >> w;                      // wire w = bit (3-w)
#pragma unroll
            for (int i0 = 0; i0 < 16; i0++) {
                if (i0 & mask) continue;
                const int i1 = i0 | mask;
                float2 a0 = amp[i0], a1 = amp[i1];
                amp[i0] = cadd(cmul(U00, a0), cmul(U01, a1));
                amp[i1] = cadd(cmul(U10, a0), cmul(U11, a1));
            }
        }
        // CNOT ring: (0,1),(1,2),(2,3),(3,0)
#pragma unroll
        for (int c = 0; c < NQ; c++) {
            const int t = (c + 1) & 3;
            const int cmsk = 8 >> c, tmsk = 8 >> t;
#pragma unroll
            for (int i = 0; i < 16; i++) {
                if ((i & cmsk) && !(i & tmsk)) {
                    float2 tmp = amp[i];
                    amp[i] = amp[i | tmsk];
                    amp[i | tmsk] = tmp;
                }
            }
        }
    }
}

// Kernel A: one tiny block computes U and stores f16 planes into ws:
// dwords [0..127] = re plane (row r = dwords 8r..8r+7, dword q = f16 pair
// (j=2q,2q+1)), dwords [128..255] = im plane. 1 KB total.
__global__ void build_u_kernel(const float* __restrict__ qw, _Float16* __restrict__ Uw) {
    const int tid = threadIdx.x;
    if (tid < 16) {
        float2 amp[16];
        build_u_col(qw, tid, amp);
        _Float16* wre = Uw;
        _Float16* wim = Uw + 256;
#pragma unroll
        for (int i = 0; i < 16; i++) {
            wre[i * 16 + tid] = (_Float16)amp[i].x;
            wim[i * 16 + tid] = (_Float16)amp[i].y;
        }
    }
}

// Kernel B: matvec with U held in SGPRs (uniform scalar loads from ws).
// No LDS anywhere; VGPR live set ~= psh(32)+ow(16)+addr -> high occupancy.
__global__ __launch_bounds__(BLK) void vqc_main(const float* __restrict__ x,
                                                const unsigned* __restrict__ Us,
                                                float* __restrict__ out, int B) {
    const int tid = threadIdx.x;
    const int base = blockIdx.x * (BLK * K) + tid;

    // ---- load x, RY encoding -> psi in f16 pairs over j ----
    bool val[K];
    unsigned psh[K][8];     // psh[el][q] = {psi[2q], psi[2q+1]} as 2xf16
#pragma unroll
    for (int k = 0; k < K; k++) {
        const int b = base + k * BLK;
        val[k] = (b < B);
        const float4 v = val[k] ? ((const float4*)x)[b] : make_float4(0.f, 0.f, 0.f, 0.f);
        const float R = 0.07957747154594767f;   // 1/(4*pi): sin(x/2)=v_sin(x*R)
        float s0 = __builtin_amdgcn_sinf(v.x * R), c0 = __builtin_amdgcn_cosf(v.x * R);
        float s1 = __builtin_amdgcn_sinf(v.y * R), c1 = __builtin_amdgcn_cosf(v.y * R);
        float s2 = __builtin_amdgcn_sinf(v.z * R), c2 = __builtin_amdgcn_cosf(v.z * R);
        float s3 = __builtin_amdgcn_sinf(v.w * R), c3 = __builtin_amdgcn_cosf(v.w * R);
        const float a01[4] = {c0 * c1, c0 * s1, s0 * c1, s0 * s1};
        const float a23[4] = {c2 * c3, c2 * s3, s2 * c3, s2 * s3};
#pragma unroll
        for (int q = 0; q < 8; q++) {
            const int j0 = 2 * q, j1 = 2 * q + 1;
            psh[k][q] = pack2h(a01[j0 >> 2] * a23[j0 & 3], a01[j1 >> 2] * a23[j1 & 3]);
        }
    }

    float ow0[K], ow1[K], ow2[K], ow3[K];
#pragma unroll
    for (int k = 0; k < K; k++) { ow0[k] = 0.f; ow1[k] = 0.f; ow2[k] = 0.f; ow3[k] = 0.f; }

    // ---- matvec: row-pair loop; U rows come in via uniform scalar loads ----
#pragma unroll 1
    for (int rp = 0; rp < 8; rp++) {
        // Uniform (wave-invariant) addresses -> s_load_dwordxN into SGPRs.
        // readfirstlane pins the values to SGPRs even if scalarization fails.
        unsigned ur[16], ui[16];   // ur[0..7]=re row 2rp, ur[8..15]=re row 2rp+1
#pragma unroll
        for (int j = 0; j < 16; j++) {
            ur[j] = __builtin_amdgcn_readfirstlane(Us[rp * 16 + j]);
            ui[j] = __builtin_amdgcn_readfirstlane(Us[128 + rp * 16 + j]);
        }

        const float f3 = (rp & 4) ? -1.f : 1.f;   // bit3 of row -> wire0
        const float f2 = (rp & 2) ? -1.f : 1.f;   // bit2 -> wire1
        const float f1 = (rp & 1) ? -1.f : 1.f;   // bit1 -> wire2

#pragma unroll
        for (int k = 0; k < K; k++) {
            float fre0 = 0.f, fim0 = 0.f, fre1 = 0.f, fim1 = 0.f;
#pragma unroll
            for (int q = 0; q < 8; q++) {
                const unsigned p = psh[k][q];
                fre0 = fdot2u(ur[q], p, fre0);
                fim0 = fdot2u(ui[q], p, fim0);
                fre1 = fdot2u(ur[8 + q], p, fre1);
                fim1 = fdot2u(ui[8 + q], p, fim1);
            }
            const float p0 = fmaf(fim0, fim0, fre0 * fre0);
            const float p1 = fmaf(fim1, fim1, fre1 * fre1);
            const float s = p0 + p1, d = p0 - p1;
            ow0[k] = fmaf(f3, s, ow0[k]);
            ow1[k] = fmaf(f2, s, ow1[k]);
            ow2[k] = fmaf(f1, s, ow2[k]);
            ow3[k] += d;                          // bit0 -> wire3
        }
    }

#pragma unroll
    for (int k = 0; k < K; k++) {
        const int b = base + k * BLK;
        if (val[k])
            ((float4*)out)[b] = make_float4(ow0[k], ow1[k], ow2[k], ow3[k]);
    }
}

// Fallback if ws too small (normally unused): fused build via LDS broadcast.
__global__ void vqc_fused(const float* __restrict__ x, const float* __restrict__ qw,
                          float* __restrict__ out, int B) {
    __shared__ __align__(16) unsigned Upl[256];
    const int tid = threadIdx.x;
    if (tid < 16) {
        float2 amp[16];
        build_u_col(qw, tid, amp);
        _Float16* wre = (_Float16*)Upl;
        _Float16* wim = wre + 256;
#pragma unroll
        for (int i = 0; i < 16; i++) {
            wre[i * 16 + tid] = (_Float16)amp[i].x;
            wim[i * 16 + tid] = (_Float16)amp[i].y;
        }
    }
    __syncthreads();

    const int base = blockIdx.x * (BLK * K) + tid;
    bool val[K];
    unsigned psh[K][8];
#pragma unroll
    for (int k = 0; k < K; k++) {
        const int b = base + k * BLK;
        val[k] = (b < B);
        const float4 v = val[k] ? ((const float4*)x)[b] : make_float4(0.f, 0.f, 0.f, 0.f);
        const float R = 0.07957747154594767f;
        float s0 = __builtin_amdgcn_sinf(v.x * R), c0 = __builtin_amdgcn_cosf(v.x * R);
        float s1 = __builtin_amdgcn_sinf(v.y * R), c1 = __builtin_amdgcn_cosf(v.y * R);
        float s2 = __builtin_amdgcn_sinf(v.z * R), c2 = __builtin_amdgcn_cosf(v.z * R);
        float s3 = __builtin_amdgcn_sinf(v.w * R), c3 = __builtin_amdgcn_cosf(v.w * R);
        const float a01[4] = {c0 * c1, c0 * s1, s0 * c1, s0 * s1};
        const float a23[4] = {c2 * c3, c2 * s3, s2 * c3, s2 * s3};
#pragma unroll
        for (int q = 0; q < 8; q++) {
            const int j0 = 2 * q, j1 = 2 * q + 1;
            psh[k][q] = pack2h(a01[j0 >> 2] * a23[j0 & 3], a01[j1 >> 2] * a23[j1 & 3]);
        }
    }

    float ow0[K], ow1[K], ow2[K], ow3[K];
#pragma unroll
    for (int k = 0; k < K; k++) { ow0[k] = 0.f; ow1[k] = 0.f; ow2[k] = 0.f; ow3[k] = 0.f; }

#pragma unroll 1
    for (int rp = 0; rp < 8; rp++) {
        unsigned ur[16], ui[16];
#pragma unroll
        for (int j = 0; j < 16; j++) {
            ur[j] = __builtin_amdgcn_readfirstlane(Upl[rp * 16 + j]);
            ui[j] = __builtin_amdgcn_readfirstlane(Upl[128 + rp * 16 + j]);
        }
        const float f3 = (rp & 4) ? -1.f : 1.f;
        const float f2 = (rp & 2) ? -1.f : 1.f;
        const float f1 = (rp & 1) ? -1.f : 1.f;
#pragma unroll
        for (int k = 0; k < K; k++) {
            float fre0 = 0.f, fim0 = 0.f, fre1 = 0.f, fim1 = 0.f;
#pragma unroll
            for (int q = 0; q < 8; q++) {
                const unsigned p = psh[k][q];
                fre0 = fdot2u(ur[q], p, fre0);
                fim0 = fdot2u(ui[q], p, fim0);
                fre1 = fdot2u(ur[8 + q], p, fre1);
                fim1 = fdot2u(ui[8 + q], p, fim1);
            }
            const float p0 = fmaf(fim0, fim0, fre0 * fre0);
            const float p1 = fmaf(fim1, fim1, fre1 * fre1);
            const float s = p0 + p1, d = p0 - p1;
            ow0[k] = fmaf(f3, s, ow0[k]);
            ow1[k] = fmaf(f2, s, ow1[k]);
            ow2[k] = fmaf(f1, s, ow2[k]);
            ow3[k] += d;
        }
    }

#pragma unroll
    for (int k = 0; k < K; k++) {
        const int b = base + k * BLK;
        if (val[k])
            ((float4*)out)[b] = make_float4(ow0[k], ow1[k], ow2[k], ow3[k]);
    }
}

extern "C" void kernel_launch(void* const* d_in, const int* in_sizes, int n_in,
                              void* d_out, int out_size, void* d_ws, size_t ws_size,
                              hipStream_t stream) {
    const float* x  = (const float*)d_in[0];
    const float* qw = (const float*)d_in[1];
    float* out = (float*)d_out;
    const int B = in_sizes[0] / NQ;
    const int blocks = (B + BLK * K - 1) / (BLK * K);

    if (ws_size >= 1024) {
        build_u_kernel<<<1, 64, 0, stream>>>(qw, (_Float16*)d_ws);
        vqc_main<<<blocks, BLK, 0, stream>>>(x, (const unsigned*)d_ws, out, B);
    } else {
        vqc_fused<<<blocks, BLK, 0, stream>>>(x, qw, out, B);
    }
}